// Round 4
// baseline (412.307 us; speedup 1.0000x reference)
//
#include <hip/hip_runtime.h>

#define NN 2048
#define DD 128

typedef _Float16 f16x8 __attribute__((ext_vector_type(8)));
typedef float f32x4 __attribute__((ext_vector_type(4)));

// ---------------------------------------------------------------------------
// prep: Wt[l][d][k] = fp16(W[l][k][d])
// ---------------------------------------------------------------------------
__global__ __launch_bounds__(256) void prep_kernel(
    const float* __restrict__ W, _Float16* __restrict__ Wt) {
  int idx = blockIdx.x * 256 + threadIdx.x;
  int l = idx >> 14, r = idx & 16383, d = r >> 7, k = r & 127;
  Wt[idx] = (_Float16)W[l * 16384 + k * 128 + d];
}

// ---------------------------------------------------------------------------
// gemmY: Yt[b][d][n] = sum_k X[b][n][k] * Wt[d][k].  LDS-free, barrier-free.
// 512 blocks x 256 thr.
// ---------------------------------------------------------------------------
template<bool F32IN>
__global__ __launch_bounds__(256) void gemmY_kernel(
    const void* __restrict__ Xin, const _Float16* __restrict__ Wt,
    _Float16* __restrict__ Yt) {
  const int bx = blockIdx.x;
  const int batch = bx & 7, n0 = (bx >> 3) * 32;
  const int tid = threadIdx.x, lane = tid & 63, wave = tid >> 6;
  const int quad = lane >> 4, l15 = lane & 15, d0 = wave * 32;
  f32x4 acc[2][2] = {};
#pragma unroll
  for (int kk = 0; kk < 128; kk += 32) {
    f16x8 a0 = *(const f16x8*)(Wt + (d0 + l15) * DD + kk + quad * 8);
    f16x8 a1 = *(const f16x8*)(Wt + (d0 + 16 + l15) * DD + kk + quad * 8);
#pragma unroll
    for (int fi = 0; fi < 2; ++fi) {
      f16x8 b;
      if (F32IN) {
        const float* xp = (const float*)Xin +
            (size_t)(batch * NN + n0 + fi * 16 + l15) * DD + kk + quad * 8;
        float4 x0 = *(const float4*)xp;
        float4 x1 = *(const float4*)(xp + 4);
        b = f16x8{(_Float16)x0.x, (_Float16)x0.y, (_Float16)x0.z, (_Float16)x0.w,
                  (_Float16)x1.x, (_Float16)x1.y, (_Float16)x1.z, (_Float16)x1.w};
      } else {
        b = *(const f16x8*)((const _Float16*)Xin +
            (size_t)(batch * NN + n0 + fi * 16 + l15) * DD + kk + quad * 8);
      }
      acc[0][fi] = __builtin_amdgcn_mfma_f32_16x16x32_f16(a0, b, acc[0][fi], 0, 0, 0);
      acc[1][fi] = __builtin_amdgcn_mfma_f32_16x16x32_f16(a1, b, acc[1][fi], 0, 0, 0);
    }
  }
  _Float16* YtB = Yt + (size_t)batch * DD * NN;
#pragma unroll
  for (int df = 0; df < 2; ++df)
#pragma unroll
    for (int fi = 0; fi < 2; ++fi)
#pragma unroll
      for (int r = 0; r < 4; ++r)
        YtB[(size_t)(d0 + df * 16 + quad * 4 + r) * NN + n0 + fi * 16 + l15] =
            (_Float16)acc[df][fi][r];
}

// ---------------------------------------------------------------------------
// agg: Zt[d][i] = sum_j Yt[d][j]*adj[i][j]; act = relu((Z+b)/(rowsum+1))
// ZERO barriers in k-loop: B-frag (adj rows) and A-frag (Yt rows) are loaded
// straight from global into MFMA register layout; depth-2 register pipeline.
// Wave = 32 i x 32 d; block = 128 thr = 32 i x 64 d; grid 1024 (4 blk/CU,
// batch-pinned to an XCD via bx&7 so Yt/adjh re-reads stay in that L2).
// FIRST: reads fp32 adj, stores converted fp16 adjh + rdg (row reciprocals).
// Layers 2/3 read the half-size adjh and rdg.
// ---------------------------------------------------------------------------
template<bool FIRST, bool LAST>
__global__ __launch_bounds__(128) void agg_kernel(
    const float* __restrict__ adj, _Float16* __restrict__ adjh,
    const _Float16* __restrict__ Yt, const float* __restrict__ bias,
    float* __restrict__ rdg, _Float16* __restrict__ act,
    float* __restrict__ out) {
  __shared__ __align__(16) char smem[32 * 68 * 4];
  float    (*Xf)[68] = (float(*)[68])smem;     // LAST epilogue tile
  _Float16 (*Xh)[72] = (_Float16(*)[72])smem;  // !LAST epilogue tile

  const int tid = threadIdx.x, bx = blockIdx.x;
  const int batch = bx & 7;
  const int idx = bx >> 3;                 // 0..127 within batch
  const int i0 = (idx >> 1) * 32;
  const int dB = (idx & 1) * 64;
  const int lane = tid & 63, dh = tid >> 6;
  const int quad = lane >> 4, l15 = lane & 15;

  const float*    bp0 = adj  + (size_t)(batch * NN + i0 + l15) * NN + quad * 8;
  const float*    bp1 = bp0 + (size_t)16 * NN;
  _Float16*       sp0 = adjh + (size_t)(batch * NN + i0 + l15) * NN + quad * 8;
  _Float16*       sp1 = sp0 + (size_t)16 * NN;
  const _Float16* hp0 = adjh + (size_t)(batch * NN + i0 + l15) * NN + quad * 8;
  const _Float16* hp1 = hp0 + (size_t)16 * NN;
  const _Float16* ap0 = Yt + (size_t)batch * DD * NN +
                        (size_t)(dB + dh * 32 + l15) * NN + quad * 8;
  const _Float16* ap1 = ap0 + (size_t)16 * NN;
  const bool storeAdj = FIRST && (idx & 1) == 0 && dh == 0;

  f32x4 acc[2][2] = {};      // [af(d)][fi(i)]
  float rs0 = 0.f, rs1 = 0.f;

  f16x8 a[2][2];             // [buf][af]
  float4 bf[2][2][2];        // [buf][fi][half]   (FIRST)
  f16x8 bh[2][2];            // [buf][fi]         (!FIRST)

#define LDB(ks, buf)                                            \
  do {                                                          \
    if (FIRST) {                                                \
      bf[buf][0][0] = *(const float4*)(bp0 + (ks));             \
      bf[buf][0][1] = *(const float4*)(bp0 + (ks) + 4);         \
      bf[buf][1][0] = *(const float4*)(bp1 + (ks));             \
      bf[buf][1][1] = *(const float4*)(bp1 + (ks) + 4);         \
    } else {                                                    \
      bh[buf][0] = *(const f16x8*)(hp0 + (ks));                 \
      bh[buf][1] = *(const f16x8*)(hp1 + (ks));                 \
    }                                                           \
    a[buf][0] = *(const f16x8*)(ap0 + (ks));                    \
    a[buf][1] = *(const f16x8*)(ap1 + (ks));                    \
  } while (0)

  LDB(0, 0);
  LDB(32, 1);

#pragma unroll 4
  for (int s = 0; s < 64; ++s) {
    const int buf = s & 1;
    f16x8 b0, b1;
    if (FIRST) {
      float4 x0 = bf[buf][0][0], x1 = bf[buf][0][1];
      float4 y0 = bf[buf][1][0], y1 = bf[buf][1][1];
      rs0 += ((x0.x + x0.y) + (x0.z + x0.w)) + ((x1.x + x1.y) + (x1.z + x1.w));
      rs1 += ((y0.x + y0.y) + (y0.z + y0.w)) + ((y1.x + y1.y) + (y1.z + y1.w));
      b0 = f16x8{(_Float16)x0.x, (_Float16)x0.y, (_Float16)x0.z, (_Float16)x0.w,
                 (_Float16)x1.x, (_Float16)x1.y, (_Float16)x1.z, (_Float16)x1.w};
      b1 = f16x8{(_Float16)y0.x, (_Float16)y0.y, (_Float16)y0.z, (_Float16)y0.w,
                 (_Float16)y1.x, (_Float16)y1.y, (_Float16)y1.z, (_Float16)y1.w};
      if (storeAdj) {
        *(f16x8*)(sp0 + s * 32) = b0;
        *(f16x8*)(sp1 + s * 32) = b1;
      }
    } else {
      b0 = bh[buf][0];
      b1 = bh[buf][1];
    }
    f16x8 a0c = a[buf][0], a1c = a[buf][1];
    if (s < 62) LDB((s + 2) * 32, buf);   // depth-2 prefetch, no barriers
    acc[0][0] = __builtin_amdgcn_mfma_f32_16x16x32_f16(a0c, b0, acc[0][0], 0, 0, 0);
    acc[0][1] = __builtin_amdgcn_mfma_f32_16x16x32_f16(a0c, b1, acc[0][1], 0, 0, 0);
    acc[1][0] = __builtin_amdgcn_mfma_f32_16x16x32_f16(a1c, b0, acc[1][0], 0, 0, 0);
    acc[1][1] = __builtin_amdgcn_mfma_f32_16x16x32_f16(a1c, b1, acc[1][1], 0, 0, 0);
  }
#undef LDB

  // row reciprocals
  float rdv0, rdv1;
  if (FIRST) {
    rs0 += __shfl_xor(rs0, 16); rs0 += __shfl_xor(rs0, 32);
    rs1 += __shfl_xor(rs1, 16); rs1 += __shfl_xor(rs1, 32);
    rdv0 = 1.0f / (rs0 + 1.0f);
    rdv1 = 1.0f / (rs1 + 1.0f);
    if (storeAdj && quad == 0) {
      rdg[batch * NN + i0 + l15] = rdv0;
      rdg[batch * NN + i0 + 16 + l15] = rdv1;
    }
  } else {
    rdv0 = rdg[batch * NN + i0 + l15];
    rdv1 = rdg[batch * NN + i0 + 16 + l15];
  }

  // epilogue: bias + scale + relu, transpose via LDS, coalesced store
#pragma unroll
  for (int af = 0; af < 2; ++af)
#pragma unroll
    for (int r = 0; r < 4; ++r) {
      int dl = dh * 32 + af * 16 + quad * 4 + r;
      float bv = bias[dB + dl];
      float v0 = fmaxf((acc[af][0][r] + bv) * rdv0, 0.f);
      float v1 = fmaxf((acc[af][1][r] + bv) * rdv1, 0.f);
      if (LAST) { Xf[l15][dl] = v0;            Xf[16 + l15][dl] = v1; }
      else      { Xh[l15][dl] = (_Float16)v0;  Xh[16 + l15][dl] = (_Float16)v1; }
    }
  __syncthreads();

  if (LAST) {
    float* ob = out + (size_t)(batch * NN + i0) * DD + dB;
#pragma unroll
    for (int u = 0; u < 4; ++u) {
      int c = tid + 128 * u;            // 512 float4s (32 rows x 16)
      int i = c >> 4, f4 = (c & 15) * 4;
      *(float4*)(ob + (size_t)i * DD + f4) = *(const float4*)&Xf[i][f4];
    }
  } else {
    _Float16* ab = act + (size_t)(batch * NN + i0) * DD + dB;
#pragma unroll
    for (int u = 0; u < 2; ++u) {
      int c = tid + 128 * u;            // 256 16-B chunks (32 rows x 8)
      int i = c >> 3, h = (c & 7) * 8;
      *(uint4*)(ab + (size_t)i * DD + h) = *(const uint4*)&Xh[i][h];
    }
  }
}

extern "C" void kernel_launch(void* const* d_in, const int* in_sizes, int n_in,
                              void* d_out, int out_size, void* d_ws, size_t ws_size,
                              hipStream_t stream) {
  const float* x0   = (const float*)d_in[0];   // [8,2048,128]
  const float* adj  = (const float*)d_in[1];   // [8,2048,2048]
  const float* W    = (const float*)d_in[2];   // [3,128,128]
  const float* bias = (const float*)d_in[3];   // [3,128]
  float* out = (float*)d_out;

  char* ws = (char*)d_ws;
  _Float16* Wt   = (_Float16*)ws;                       // 96 KB
  float*    rdg  = (float*)(ws + (1u << 17));           // 64 KB
  _Float16* YtA  = (_Float16*)(ws + (1u << 20));        // 4 MB
  _Float16* YtB  = (_Float16*)(ws + 6u * (1u << 20));   // 4 MB
  _Float16* actA = (_Float16*)(ws + 11u * (1u << 20));  // 4 MB
  _Float16* actB = (_Float16*)(ws + 16u * (1u << 20));  // 4 MB
  _Float16* adjh = (_Float16*)(ws + 32u * (1u << 20));  // 64 MB

  prep_kernel        <<<192, 256, 0, stream>>>(W, Wt);
  gemmY_kernel<true> <<<512, 256, 0, stream>>>(x0, Wt, YtA);
  agg_kernel<true , false><<<1024, 128, 0, stream>>>(adj, adjh, YtA, bias,       rdg, actA, nullptr);
  gemmY_kernel<false><<<512, 256, 0, stream>>>(actA, Wt + 16384, YtB);
  agg_kernel<false, false><<<1024, 128, 0, stream>>>(adj, adjh, YtB, bias + 128, rdg, actB, nullptr);
  gemmY_kernel<false><<<512, 256, 0, stream>>>(actB, Wt + 32768, YtA);
  agg_kernel<false, true ><<<1024, 128, 0, stream>>>(adj, adjh, YtA, bias + 256, rdg, nullptr, out);
}